// Round 1
// baseline (216.067 us; speedup 1.0000x reference)
//
#include <hip/hip_runtime.h>
#include <math.h>

#define NSEG 7320
#define NLON 120
#define HIDN 128
#define ECH  16     // entries per k2 block chunk
#define MAXCH 36    // 36*16 = 576-entry cap per row (max row ~520; R4/R6-proven)

// ---------------------------------------------------------------------------
// K1: grp 0-11: LN0 + QKV projection. Interleaved per-head layout:
// q_i/k_i/v_i are [4][NSEG][16] so k2 reads one 64B line per neighbor point
// (4x dwordx4 with imm offsets) instead of 16 strided scalars.
// grp = mm*4 + head; each thread computes 16 channels of one head.
// q pre-scaled by 1/sqrt(DH)=0.25.
// grp 12: meta {hi*120, dl, qw bits, ho} + per-lat-row CSR offsets.
// grp 13-14: zero num[64][NSEG]+den[4][NSEG] (contiguous, float4 stride loop).
// ---------------------------------------------------------------------------
__global__ __launch_bounds__(64) void k1_ln_qkv(
    const float* __restrict__ x,  const float* __restrict__ wq,
    const float* __restrict__ wk, const float* __restrict__ wv,
    const float* __restrict__ g,  const float* __restrict__ b,
    const int* __restrict__ out_idx, const int* __restrict__ in_idx,
    const float* __restrict__ qw, int E,
    float* __restrict__ q_i, float* __restrict__ k_i, float* __restrict__ v_i,
    int* __restrict__ row_start, int4* __restrict__ meta,
    float4* __restrict__ zbase)
{
    const int lane = threadIdx.x;
    const int tile = blockIdx.x;
    const int grp  = blockIdx.y;

    if (grp >= 13) {                       // zero num+den: 68*NSEG floats
        const int n4 = (68 * NSEG) / 4;
        for (int i = ((grp - 13) * 115 + tile) * 64 + lane; i < n4; i += 2 * 115 * 64)
            zbase[i] = make_float4(0.f, 0.f, 0.f, 0.f);
        return;
    }
    if (grp == 12) {                       // meta + row_start build
        for (int e = tile * 64 + lane; e < E; e += 115 * 64) {
            int ho = out_idx[e * NLON] / NLON;
            if (e == 0) {
                row_start[ho] = 0;
            } else {
                int hp = out_idx[(e - 1) * NLON] / NLON;
                if (hp != ho) row_start[ho] = e;
            }
            if (e == E - 1) row_start[ho + 1] = E;
            int i0 = in_idx[e * NLON];     // wo = 0 column: hi*120 + dl
            int hi = i0 / NLON;
            int dl = i0 - hi * NLON;
            meta[e] = make_int4(hi * NLON, dl, __float_as_int(qw[i0]), ho);
        }
        return;
    }

    const int n = tile * 64 + lane;
    if (n >= NSEG) return;

    float xv[64];
    float s = 0.f, s2 = 0.f;
#pragma unroll
    for (int c = 0; c < 64; ++c) { float t = x[c * NSEG + n]; xv[c] = t; s += t; s2 += t * t; }
    float mean = s * 0.015625f;
    float var  = s2 * 0.015625f - mean * mean;
    float rstd = rsqrtf(var + 1e-6f);
#pragma unroll
    for (int c = 0; c < 64; ++c) xv[c] = (xv[c] - mean) * rstd * g[c] + b[c];

    const int mm   = grp >> 2;             // 0=q 1=k 2=v
    const int head = grp & 3;
    const float* __restrict__ w = (mm == 0) ? wq : (mm == 1) ? wk : wv;
    float* __restrict__ dst = (mm == 0) ? q_i : (mm == 1) ? k_i : v_i;
    const float scale = (mm == 0) ? 0.25f : 1.0f;

    float acc[16];
#pragma unroll
    for (int j = 0; j < 16; ++j) {
        const float* __restrict__ wr = w + (head * 16 + j) * 64;
        float a = 0.f;
#pragma unroll
        for (int c = 0; c < 64; ++c) a += wr[c] * xv[c];
        acc[j] = a * scale;
    }

    float4* __restrict__ dp = (float4*)(dst + (((size_t)head * NSEG + n) << 4));
    dp[0] = make_float4(acc[0],  acc[1],  acc[2],  acc[3]);
    dp[1] = make_float4(acc[4],  acc[5],  acc[6],  acc[7]);
    dp[2] = make_float4(acc[8],  acc[9],  acc[10], acc[11]);
    dp[3] = make_float4(acc[12], acc[13], acc[14], acc[15]);
}

// ---------------------------------------------------------------------------
// K2: fused scores + PV, one HEAD per block. Block (row ho, 16-entry chunk,
// head), 128 thr, lane = wo. With [4][NSEG][16] layout each entry is one
// 64B line per lane for k and one for v: 4x dwordx4 @ imm offsets (vs 32
// strided scalar loads each needing its own 64-bit addr add — NSEG*4 doesn't
// fit the 13-bit imm). Per-entry issue count ~140 -> ~55.
// Epilogue: 16 num + 1 den atomics/lane (num/den stay planar -> coalesced).
// No-max softmax (scores O(+-8); R2..R8 validated).
// ---------------------------------------------------------------------------
__global__ __launch_bounds__(128) void k2_attn(
    const float* __restrict__ q_i, const float* __restrict__ k_i,
    const float* __restrict__ v_i,
    const int4* __restrict__ meta,  const int* __restrict__ row_start,
    float* __restrict__ num, float* __restrict__ den)
{
    const int wo  = threadIdx.x;           // 0..127
    const bool aw = wo < NLON;
    const int woc = aw ? wo : (NLON - 1);
    const int ho  = blockIdx.x;
    const int head = blockIdx.z;           // 0..3
    const int cb  = head * 16;

    int e0 = __builtin_amdgcn_readfirstlane(row_start[ho]);
    int e1 = __builtin_amdgcn_readfirstlane(row_start[ho + 1]);
    int eb = e0 + blockIdx.y * ECH;
    if (eb >= e1) return;
    int ee = eb + ECH; if (ee > e1) ee = e1;

    const int segc = ho * NLON + woc;
    const float4* __restrict__ qp =
        (const float4*)(q_i + (((size_t)head * NSEG + segc) << 4));
    const float4 q0 = qp[0], q1 = qp[1], q2 = qp[2], q3 = qp[3];

    const float* __restrict__ kbase = k_i + (((size_t)head * NSEG) << 4);
    const float* __restrict__ vbase = v_i + (((size_t)head * NSEG) << 4);

    float acc[16];
#pragma unroll
    for (int c = 0; c < 16; ++c) acc[c] = 0.f;
    float dh = 0.f;

#pragma unroll 2
    for (int e = eb; e < ee; ++e) {
        int4 mt = meta[e];
        int dlw = mt.y + woc; if (dlw >= NLON) dlw -= NLON;
        const size_t poff = ((size_t)(mt.x + dlw)) << 4;
        const float4* __restrict__ kp = (const float4*)(kbase + poff);
        const float4* __restrict__ vp = (const float4*)(vbase + poff);

        float4 ka = kp[0], kb = kp[1], kc = kp[2], kd = kp[3];
        float sa = q0.x * ka.x; sa = fmaf(q0.y, ka.y, sa); sa = fmaf(q0.z, ka.z, sa); sa = fmaf(q0.w, ka.w, sa);
        float sb = q1.x * kb.x; sb = fmaf(q1.y, kb.y, sb); sb = fmaf(q1.z, kb.z, sb); sb = fmaf(q1.w, kb.w, sb);
        float sc = q2.x * kc.x; sc = fmaf(q2.y, kc.y, sc); sc = fmaf(q2.z, kc.z, sc); sc = fmaf(q2.w, kc.w, sc);
        float sd = q3.x * kd.x; sd = fmaf(q3.y, kd.y, sd); sd = fmaf(q3.z, kd.z, sd); sd = fmaf(q3.w, kd.w, sd);
        float sscore = (sa + sb) + (sc + sd);

        float qwv = aw ? __int_as_float(mt.z) : 0.f;
        float a = __expf(sscore) * qwv;
        dh += a;

        float4 va = vp[0], vb = vp[1], vc = vp[2], vd = vp[3];
        acc[0]  = fmaf(a, va.x, acc[0]);  acc[1]  = fmaf(a, va.y, acc[1]);
        acc[2]  = fmaf(a, va.z, acc[2]);  acc[3]  = fmaf(a, va.w, acc[3]);
        acc[4]  = fmaf(a, vb.x, acc[4]);  acc[5]  = fmaf(a, vb.y, acc[5]);
        acc[6]  = fmaf(a, vb.z, acc[6]);  acc[7]  = fmaf(a, vb.w, acc[7]);
        acc[8]  = fmaf(a, vc.x, acc[8]);  acc[9]  = fmaf(a, vc.y, acc[9]);
        acc[10] = fmaf(a, vc.z, acc[10]); acc[11] = fmaf(a, vc.w, acc[11]);
        acc[12] = fmaf(a, vd.x, acc[12]); acc[13] = fmaf(a, vd.y, acc[13]);
        acc[14] = fmaf(a, vd.z, acc[14]); acc[15] = fmaf(a, vd.w, acc[15]);
    }

    if (aw) {
        const int seg = ho * NLON + wo;
#pragma unroll
        for (int c = 0; c < 16; ++c) atomicAdd(&num[(cb + c) * NSEG + seg], acc[c]);
        atomicAdd(&den[head * NSEG + seg], dh);
    }
}

// ---------------------------------------------------------------------------
// K2c: att = num/den, Wo projection + residual -> x1 planar.
// grid (115, 8): 8 output channels per group; thread-per-point, all planar.
// ---------------------------------------------------------------------------
__global__ __launch_bounds__(64) void k2c_wo(
    const float* __restrict__ num, const float* __restrict__ den,
    const float* __restrict__ wo,  const float* __restrict__ x,
    float* __restrict__ x1)
{
    const int lane = threadIdx.x;
    const int n    = blockIdx.x * 64 + lane;
    if (n >= NSEG) return;

    float rdh[4];
#pragma unroll
    for (int h = 0; h < 4; ++h) rdh[h] = 1.0f / den[h * NSEG + n];

    float att[64];
#pragma unroll
    for (int c = 0; c < 64; ++c) att[c] = num[c * NSEG + n] * rdh[c >> 4];

    const int o0 = blockIdx.y * 8;
#pragma unroll
    for (int j = 0; j < 8; ++j) {
        int o = o0 + j;
        float acc = 0.f;
#pragma unroll
        for (int c = 0; c < 64; ++c) acc += wo[o * 64 + c] * att[c];
        x1[o * NSEG + n] = acc + x[o * NSEG + n];
    }
}

// ---------------------------------------------------------------------------
// K3a: LayerNorm1 + W1 + exact gelu -> m_act planar [128][NSEG].
// grid (115, 16): 8 hidden units per group (1840 waves for latency hiding).
// ---------------------------------------------------------------------------
__global__ __launch_bounds__(64) void k3a_mlp1(
    const float* __restrict__ x1, const float* __restrict__ w1,
    const float* __restrict__ b1, const float* __restrict__ g,
    const float* __restrict__ bb, float* __restrict__ m_act)
{
    const int lane = threadIdx.x;
    const int n    = blockIdx.x * 64 + lane;
    if (n >= NSEG) return;

    float xv[64];
    float s = 0.f, s2 = 0.f;
#pragma unroll
    for (int c = 0; c < 64; ++c) { float t = x1[c * NSEG + n]; xv[c] = t; s += t; s2 += t * t; }
    float mean = s * 0.015625f;
    float var  = s2 * 0.015625f - mean * mean;
    float rstd = rsqrtf(var + 1e-6f);
#pragma unroll
    for (int c = 0; c < 64; ++c) xv[c] = (xv[c] - mean) * rstd * g[c] + bb[c];

    const int h0 = blockIdx.y * 8;
#pragma unroll
    for (int j = 0; j < 8; ++j) {
        int h = h0 + j;
        float mh = b1[h];
#pragma unroll
        for (int c = 0; c < 64; ++c) mh += w1[h * 64 + c] * xv[c];
        m_act[h * NSEG + n] = 0.5f * mh * (1.0f + erff(mh * 0.70710678118654752f));
    }
}

// ---------------------------------------------------------------------------
// K3b: out = W2 * m_act + b2 + x1. grid (115, 8): 8 output channels/group.
// ---------------------------------------------------------------------------
__global__ __launch_bounds__(64) void k3b_mlp2(
    const float* __restrict__ m_act, const float* __restrict__ w2,
    const float* __restrict__ b2,    const float* __restrict__ x1,
    float* __restrict__ out)
{
    const int lane = threadIdx.x;
    const int n    = blockIdx.x * 64 + lane;
    if (n >= NSEG) return;
    const int c0   = blockIdx.y * 8;

    float acc[8];
#pragma unroll
    for (int j = 0; j < 8; ++j) acc[j] = 0.f;

#pragma unroll 8
    for (int h = 0; h < HIDN; ++h) {
        float mh = m_act[h * NSEG + n];
#pragma unroll
        for (int j = 0; j < 8; ++j) acc[j] += w2[(c0 + j) * HIDN + h] * mh;
    }
#pragma unroll
    for (int j = 0; j < 8; ++j) {
        int c = c0 + j;
        out[c * NSEG + n] = acc[j] + b2[c] + x1[c * NSEG + n];
    }
}

// ---------------------------------------------------------------------------
extern "C" void kernel_launch(void* const* d_in, const int* in_sizes, int n_in,
                              void* d_out, int out_size, void* d_ws, size_t ws_size,
                              hipStream_t stream)
{
    const float* x    = (const float*)d_in[0];
    const float* wq   = (const float*)d_in[1];
    const float* wk   = (const float*)d_in[2];
    const float* wv   = (const float*)d_in[3];
    const float* wo   = (const float*)d_in[4];
    const float* w1   = (const float*)d_in[5];
    const float* b1   = (const float*)d_in[6];
    const float* w2   = (const float*)d_in[7];
    const float* b2   = (const float*)d_in[8];
    const float* ln0g = (const float*)d_in[9];
    const float* ln0b = (const float*)d_in[10];
    const float* ln1g = (const float*)d_in[11];
    const float* ln1b = (const float*)d_in[12];
    const float* qw   = (const float*)d_in[13];
    const int* out_idx = (const int*)d_in[14];
    const int* in_idx  = (const int*)d_in[15];
    float* out = (float*)d_out;

    const int NNZ = in_sizes[15];
    const int E   = NNZ / NLON;
    const size_t N64 = (size_t)NSEG * 64;

    float* ws    = (float*)d_ws;
    float* q_i   = ws;                     // [4][NSEG][16]
    float* k_i   = ws + N64;               // [4][NSEG][16]
    float* v_i   = ws + 2 * N64;           // [4][NSEG][16]
    float* num   = ws + 3 * N64;           // [64][NSEG]  (zeroed by k1)
    float* den   = ws + 4 * N64;           // [4][NSEG]   (zeroed, contiguous w/ num)
    float* x1    = ws + 4 * N64 + 4 * NSEG;
    float* m_act = ws + 5 * N64 + 4 * NSEG;           // [128][NSEG]
    int*   row_start = (int*)(ws + 7 * N64 + 4 * NSEG);            // [62]
    int4*  meta  = (int4*)(ws + 7 * N64 + 4 * NSEG + 64);          // [E]

    hipLaunchKernelGGL(k1_ln_qkv, dim3(115, 15), dim3(64), 0, stream,
                       x, wq, wk, wv, ln0g, ln0b, out_idx, in_idx, qw, E,
                       q_i, k_i, v_i, row_start, meta, (float4*)num);
    hipLaunchKernelGGL(k2_attn, dim3(61, MAXCH, 4), dim3(128), 0, stream,
                       q_i, k_i, v_i, meta, row_start, num, den);
    hipLaunchKernelGGL(k2c_wo, dim3(115, 8), dim3(64), 0, stream,
                       num, den, wo, x, x1);
    hipLaunchKernelGGL(k3a_mlp1, dim3(115, 16), dim3(64), 0, stream,
                       x1, w1, b1, ln1g, ln1b, m_act);
    hipLaunchKernelGGL(k3b_mlp2, dim3(115, 8), dim3(64), 0, stream,
                       m_act, w2, b2, x1, out);
}

// Round 2
// 193.326 us; speedup vs baseline: 1.1176x; 1.1176x over previous
//
#include <hip/hip_runtime.h>
#include <math.h>

#define NSEG 7320
#define NLON 120
#define HIDN 128
#define ECH  8      // entries per k2 block chunk (R2: halved 16->8 for 2x wave supply)
#define MAXCH 68    // 68*8 = 544-entry cap per row (max row ~520; R4/R6-proven)

// ---------------------------------------------------------------------------
// K1: grp 0-23: LN0 + QKV projection (8 output channels per group), planar
// [64][NSEG] outputs, coalesced. q pre-scaled by 1/sqrt(DH)=0.25.
// grp 24: meta {hi*120, dl, qw bits, ho} + per-lat-row CSR offsets.
// grp 25-26: zero num[64][NSEG]+den[4][NSEG] (contiguous, float4 stride loop).
// (R1 interleaved-[4][NSEG][16] layout regressed: k2 fell to 32 VGPRs and
// serialized all float4 loads -> VALUBusy 6.7%. Planar's 33 independent
// scalar loads per entry ARE the latency hiding. Reverted.)
// ---------------------------------------------------------------------------
__global__ __launch_bounds__(64) void k1_ln_qkv(
    const float* __restrict__ x,  const float* __restrict__ wq,
    const float* __restrict__ wk, const float* __restrict__ wv,
    const float* __restrict__ g,  const float* __restrict__ b,
    const int* __restrict__ out_idx, const int* __restrict__ in_idx,
    const float* __restrict__ qw, int E,
    float* __restrict__ q_pl, float* __restrict__ k_pl, float* __restrict__ v_pl,
    int* __restrict__ row_start, int4* __restrict__ meta,
    float4* __restrict__ zbase)
{
    const int lane = threadIdx.x;
    const int tile = blockIdx.x;
    const int grp  = blockIdx.y;

    if (grp >= 25) {                       // zero num+den: 68*NSEG floats
        const int n4 = (68 * NSEG) / 4;
        for (int i = ((grp - 25) * 115 + tile) * 64 + lane; i < n4; i += 2 * 115 * 64)
            zbase[i] = make_float4(0.f, 0.f, 0.f, 0.f);
        return;
    }
    if (grp == 24) {                       // meta + row_start build
        for (int e = tile * 64 + lane; e < E; e += 115 * 64) {
            int ho = out_idx[e * NLON] / NLON;
            if (e == 0) {
                row_start[ho] = 0;
            } else {
                int hp = out_idx[(e - 1) * NLON] / NLON;
                if (hp != ho) row_start[ho] = e;
            }
            if (e == E - 1) row_start[ho + 1] = E;
            int i0 = in_idx[e * NLON];     // wo = 0 column: hi*120 + dl
            int hi = i0 / NLON;
            int dl = i0 - hi * NLON;
            meta[e] = make_int4(hi * NLON, dl, __float_as_int(qw[i0]), ho);
        }
        return;
    }

    const int n = tile * 64 + lane;
    if (n >= NSEG) return;

    float xv[64];
    float s = 0.f, s2 = 0.f;
#pragma unroll
    for (int c = 0; c < 64; ++c) { float t = x[c * NSEG + n]; xv[c] = t; s += t; s2 += t * t; }
    float mean = s * 0.015625f;
    float var  = s2 * 0.015625f - mean * mean;
    float rstd = rsqrtf(var + 1e-6f);
#pragma unroll
    for (int c = 0; c < 64; ++c) xv[c] = (xv[c] - mean) * rstd * g[c] + b[c];

    const int mm    = grp >> 3;            // 0=q 1=k 2=v
    const int obase = (grp & 7) * 8;
    const float* __restrict__ w = (mm == 0) ? wq : (mm == 1) ? wk : wv;
    float* __restrict__ dst = (mm == 0) ? q_pl : (mm == 1) ? k_pl : v_pl;
    const float scale = (mm == 0) ? 0.25f : 1.0f;

#pragma unroll
    for (int j = 0; j < 8; ++j) {
        int o = obase + j;
        float acc = 0.f;
#pragma unroll
        for (int c = 0; c < 64; ++c) acc += w[o * 64 + c] * xv[c];
        dst[o * NSEG + n] = acc * scale;
    }
}

// ---------------------------------------------------------------------------
// K2: fused scores + PV, one HEAD per block. Block (row ho, 8-entry chunk,
// head), 128 thr, lane = wo. Per-lane only: score = 16-ch dot of planar q/k
// (coalesced across lanes), alpha = exp(s)*qw, acc[16] += alpha*v. qreg[16]+
// acc[16] ~ 50-60 VGPRs. The 33 independent scalar loads/entry provide the
// MLP that hides L2 latency (R1 float4 rewrite collapsed this). ECH=8 (R2):
// latency-bound at 22% occupancy -> double the chunk count for 2x waves;
// epilogue atomic traffic doubles (~28 MB writes, ~2 us — cheap).
// No-max softmax (scores O(+-8); R2..R8 validated).
// ---------------------------------------------------------------------------
__global__ __launch_bounds__(128) void k2_attn(
    const float* __restrict__ q_pl, const float* __restrict__ k_pl,
    const float* __restrict__ v_pl,
    const int4* __restrict__ meta,  const int* __restrict__ row_start,
    float* __restrict__ num, float* __restrict__ den)
{
    const int wo  = threadIdx.x;           // 0..127
    const bool aw = wo < NLON;
    const int woc = aw ? wo : (NLON - 1);
    const int ho  = blockIdx.x;
    const int head = blockIdx.z;           // 0..3
    const int cb  = head * 16;

    int e0 = __builtin_amdgcn_readfirstlane(row_start[ho]);
    int e1 = __builtin_amdgcn_readfirstlane(row_start[ho + 1]);
    int eb = e0 + blockIdx.y * ECH;
    if (eb >= e1) return;
    int ee = eb + ECH; if (ee > e1) ee = e1;

    const int segc = ho * NLON + woc;
    const float* __restrict__ qb = q_pl + (size_t)cb * NSEG;
    const float* __restrict__ kb = k_pl + (size_t)cb * NSEG;
    const float* __restrict__ vb = v_pl + (size_t)cb * NSEG;

    float qreg[16];
#pragma unroll
    for (int c = 0; c < 16; ++c) qreg[c] = qb[c * NSEG + segc];

    float acc[16];
#pragma unroll
    for (int c = 0; c < 16; ++c) acc[c] = 0.f;
    float dh = 0.f;

#pragma unroll 2
    for (int e = eb; e < ee; ++e) {
        int4 mt = meta[e];
        int dlw = mt.y + woc; if (dlw >= NLON) dlw -= NLON;
        const float* __restrict__ kp = kb + (mt.x + dlw);
        const float* __restrict__ vp = vb + (mt.x + dlw);

        float sa = 0.f, sb = 0.f;
#pragma unroll
        for (int c = 0; c < 8; ++c)  sa += qreg[c]     * kp[c * NSEG];
#pragma unroll
        for (int c = 0; c < 8; ++c)  sb += qreg[8 + c] * kp[(8 + c) * NSEG];

        float qwv = aw ? __int_as_float(mt.z) : 0.f;
        float a = __expf(sa + sb) * qwv;
        dh += a;

#pragma unroll
        for (int c = 0; c < 16; ++c) acc[c] = fmaf(a, vp[c * NSEG], acc[c]);
    }

    if (aw) {
        const int seg = ho * NLON + wo;
#pragma unroll
        for (int c = 0; c < 16; ++c) atomicAdd(&num[(cb + c) * NSEG + seg], acc[c]);
        atomicAdd(&den[head * NSEG + seg], dh);
    }
}

// ---------------------------------------------------------------------------
// K2c: att = num/den, Wo projection + residual -> x1 planar.
// grid (115, 8): 8 output channels per group; thread-per-point, all planar.
// ---------------------------------------------------------------------------
__global__ __launch_bounds__(64) void k2c_wo(
    const float* __restrict__ num, const float* __restrict__ den,
    const float* __restrict__ wo,  const float* __restrict__ x,
    float* __restrict__ x1)
{
    const int lane = threadIdx.x;
    const int n    = blockIdx.x * 64 + lane;
    if (n >= NSEG) return;

    float rdh[4];
#pragma unroll
    for (int h = 0; h < 4; ++h) rdh[h] = 1.0f / den[h * NSEG + n];

    float att[64];
#pragma unroll
    for (int c = 0; c < 64; ++c) att[c] = num[c * NSEG + n] * rdh[c >> 4];

    const int o0 = blockIdx.y * 8;
#pragma unroll
    for (int j = 0; j < 8; ++j) {
        int o = o0 + j;
        float acc = 0.f;
#pragma unroll
        for (int c = 0; c < 64; ++c) acc += wo[o * 64 + c] * att[c];
        x1[o * NSEG + n] = acc + x[o * NSEG + n];
    }
}

// ---------------------------------------------------------------------------
// K3a: LayerNorm1 + W1 + exact gelu -> m_act planar [128][NSEG].
// grid (115, 16): 8 hidden units per group (1840 waves for latency hiding).
// ---------------------------------------------------------------------------
__global__ __launch_bounds__(64) void k3a_mlp1(
    const float* __restrict__ x1, const float* __restrict__ w1,
    const float* __restrict__ b1, const float* __restrict__ g,
    const float* __restrict__ bb, float* __restrict__ m_act)
{
    const int lane = threadIdx.x;
    const int n    = blockIdx.x * 64 + lane;
    if (n >= NSEG) return;

    float xv[64];
    float s = 0.f, s2 = 0.f;
#pragma unroll
    for (int c = 0; c < 64; ++c) { float t = x1[c * NSEG + n]; xv[c] = t; s += t; s2 += t * t; }
    float mean = s * 0.015625f;
    float var  = s2 * 0.015625f - mean * mean;
    float rstd = rsqrtf(var + 1e-6f);
#pragma unroll
    for (int c = 0; c < 64; ++c) xv[c] = (xv[c] - mean) * rstd * g[c] + bb[c];

    const int h0 = blockIdx.y * 8;
#pragma unroll
    for (int j = 0; j < 8; ++j) {
        int h = h0 + j;
        float mh = b1[h];
#pragma unroll
        for (int c = 0; c < 64; ++c) mh += w1[h * 64 + c] * xv[c];
        m_act[h * NSEG + n] = 0.5f * mh * (1.0f + erff(mh * 0.70710678118654752f));
    }
}

// ---------------------------------------------------------------------------
// K3b: out = W2 * m_act + b2 + x1. grid (115, 8): 8 output channels/group.
// ---------------------------------------------------------------------------
__global__ __launch_bounds__(64) void k3b_mlp2(
    const float* __restrict__ m_act, const float* __restrict__ w2,
    const float* __restrict__ b2,    const float* __restrict__ x1,
    float* __restrict__ out)
{
    const int lane = threadIdx.x;
    const int n    = blockIdx.x * 64 + lane;
    if (n >= NSEG) return;
    const int c0   = blockIdx.y * 8;

    float acc[8];
#pragma unroll
    for (int j = 0; j < 8; ++j) acc[j] = 0.f;

#pragma unroll 8
    for (int h = 0; h < HIDN; ++h) {
        float mh = m_act[h * NSEG + n];
#pragma unroll
        for (int j = 0; j < 8; ++j) acc[j] += w2[(c0 + j) * HIDN + h] * mh;
    }
#pragma unroll
    for (int j = 0; j < 8; ++j) {
        int c = c0 + j;
        out[c * NSEG + n] = acc[j] + b2[c] + x1[c * NSEG + n];
    }
}

// ---------------------------------------------------------------------------
extern "C" void kernel_launch(void* const* d_in, const int* in_sizes, int n_in,
                              void* d_out, int out_size, void* d_ws, size_t ws_size,
                              hipStream_t stream)
{
    const float* x    = (const float*)d_in[0];
    const float* wq   = (const float*)d_in[1];
    const float* wk   = (const float*)d_in[2];
    const float* wv   = (const float*)d_in[3];
    const float* wo   = (const float*)d_in[4];
    const float* w1   = (const float*)d_in[5];
    const float* b1   = (const float*)d_in[6];
    const float* w2   = (const float*)d_in[7];
    const float* b2   = (const float*)d_in[8];
    const float* ln0g = (const float*)d_in[9];
    const float* ln0b = (const float*)d_in[10];
    const float* ln1g = (const float*)d_in[11];
    const float* ln1b = (const float*)d_in[12];
    const float* qw   = (const float*)d_in[13];
    const int* out_idx = (const int*)d_in[14];
    const int* in_idx  = (const int*)d_in[15];
    float* out = (float*)d_out;

    const int NNZ = in_sizes[15];
    const int E   = NNZ / NLON;
    const size_t N64 = (size_t)NSEG * 64;

    float* ws    = (float*)d_ws;
    float* q_pl  = ws;                     // [64][NSEG]
    float* k_pl  = ws + N64;
    float* v_pl  = ws + 2 * N64;
    float* num   = ws + 3 * N64;           // [64][NSEG]  (zeroed by k1)
    float* den   = ws + 4 * N64;           // [4][NSEG]   (zeroed, contiguous w/ num)
    float* x1    = ws + 4 * N64 + 4 * NSEG;
    float* m_act = ws + 5 * N64 + 4 * NSEG;           // [128][NSEG]
    int*   row_start = (int*)(ws + 7 * N64 + 4 * NSEG);            // [62]
    int4*  meta  = (int4*)(ws + 7 * N64 + 4 * NSEG + 64);          // [E]

    hipLaunchKernelGGL(k1_ln_qkv, dim3(115, 27), dim3(64), 0, stream,
                       x, wq, wk, wv, ln0g, ln0b, out_idx, in_idx, qw, E,
                       q_pl, k_pl, v_pl, row_start, meta, (float4*)num);
    hipLaunchKernelGGL(k2_attn, dim3(61, MAXCH, 4), dim3(128), 0, stream,
                       q_pl, k_pl, v_pl, meta, row_start, num, den);
    hipLaunchKernelGGL(k2c_wo, dim3(115, 8), dim3(64), 0, stream,
                       num, den, wo, x, x1);
    hipLaunchKernelGGL(k3a_mlp1, dim3(115, 16), dim3(64), 0, stream,
                       x1, w1, b1, ln1g, ln1b, m_act);
    hipLaunchKernelGGL(k3b_mlp2, dim3(115, 8), dim3(64), 0, stream,
                       m_act, w2, b2, x1, out);
}

// Round 3
// 189.324 us; speedup vs baseline: 1.1413x; 1.0211x over previous
//
#include <hip/hip_runtime.h>
#include <math.h>

#define NSEG 7320
#define NLON 120
#define HIDN 128
#define ECHB 64     // entries per k2 block (4 subchunks x 16)
#define SUBE 16     // entries per subchunk (R0-proven per-wave serial depth)
#define NCHB 9      // 9*64 = 576-entry cap per row (max row ~520)

// ---------------------------------------------------------------------------
// K1: grp 0-47: LN0 + QKV projection (4 output channels per group), planar
// [64][NSEG] outputs, coalesced. q pre-scaled by 1/sqrt(DH)=0.25.
// R3: 8->4 ch/group doubles wave count (2760->5520) — whole pipeline was
// wave-starved (all non-k2 kernels < 2.7 waves/SIMD supply).
// grp 48: meta {hi*120, dl, qw bits, ho} + per-lat-row CSR offsets.
// grp 49-50: zero num[64][NSEG]+den[4][NSEG] (contiguous, float4 stride loop).
// ---------------------------------------------------------------------------
__global__ __launch_bounds__(64) void k1_ln_qkv(
    const float* __restrict__ x,  const float* __restrict__ wq,
    const float* __restrict__ wk, const float* __restrict__ wv,
    const float* __restrict__ g,  const float* __restrict__ b,
    const int* __restrict__ out_idx, const int* __restrict__ in_idx,
    const float* __restrict__ qw, int E,
    float* __restrict__ q_pl, float* __restrict__ k_pl, float* __restrict__ v_pl,
    int* __restrict__ row_start, int4* __restrict__ meta,
    float4* __restrict__ zbase)
{
    const int lane = threadIdx.x;
    const int tile = blockIdx.x;
    const int grp  = blockIdx.y;

    if (grp >= 49) {                       // zero num+den: 68*NSEG floats
        const int n4 = (68 * NSEG) / 4;
        for (int i = ((grp - 49) * 115 + tile) * 64 + lane; i < n4; i += 2 * 115 * 64)
            zbase[i] = make_float4(0.f, 0.f, 0.f, 0.f);
        return;
    }
    if (grp == 48) {                       // meta + row_start build
        for (int e = tile * 64 + lane; e < E; e += 115 * 64) {
            int ho = out_idx[e * NLON] / NLON;
            if (e == 0) {
                row_start[ho] = 0;
            } else {
                int hp = out_idx[(e - 1) * NLON] / NLON;
                if (hp != ho) row_start[ho] = e;
            }
            if (e == E - 1) row_start[ho + 1] = E;
            int i0 = in_idx[e * NLON];     // wo = 0 column: hi*120 + dl
            int hi = i0 / NLON;
            int dl = i0 - hi * NLON;
            meta[e] = make_int4(hi * NLON, dl, __float_as_int(qw[i0]), ho);
        }
        return;
    }

    const int n = tile * 64 + lane;
    if (n >= NSEG) return;

    float xv[64];
    float s = 0.f, s2 = 0.f;
#pragma unroll
    for (int c = 0; c < 64; ++c) { float t = x[c * NSEG + n]; xv[c] = t; s += t; s2 += t * t; }
    float mean = s * 0.015625f;
    float var  = s2 * 0.015625f - mean * mean;
    float rstd = rsqrtf(var + 1e-6f);
#pragma unroll
    for (int c = 0; c < 64; ++c) xv[c] = (xv[c] - mean) * rstd * g[c] + b[c];

    const int mm    = grp >> 4;            // 0=q 1=k 2=v
    const int obase = (grp & 15) * 4;
    const float* __restrict__ w = (mm == 0) ? wq : (mm == 1) ? wk : wv;
    float* __restrict__ dst = (mm == 0) ? q_pl : (mm == 1) ? k_pl : v_pl;
    const float scale = (mm == 0) ? 0.25f : 1.0f;

#pragma unroll
    for (int j = 0; j < 4; ++j) {
        int o = obase + j;
        float acc = 0.f;
#pragma unroll
        for (int c = 0; c < 64; ++c) acc += w[o * 64 + c] * xv[c];
        dst[o * NSEG + n] = acc * scale;
    }
}

// ---------------------------------------------------------------------------
// K2: fused scores + PV. R3 restructure — R1/R2 proved the wall is ATOMIC
// traffic + same-line contention (ECH 16->8 doubled atomics, +7.2us), not
// wave supply. Block = 512 thr = 4 subchunks x 128 lanes, covers 64 entries
// of one (row, head): each subchunk runs the R0-proven 16-entry loop into
// registers, LDS tree-reduce (17 floats/thread, conflict-free layout), then
// ONE epilogue per 64 entries: plain stores when the row fits in a single
// block (most equatorial rows), atomics otherwise. Atomics /4 vs R0, and
// the 4 subchunks share k/v L1 lines on the same CU.
// No-max softmax (scores O(+-8); validated R2..R8 of prior session).
// ---------------------------------------------------------------------------
__global__ __launch_bounds__(512) void k2_attn(
    const float* __restrict__ q_pl, const float* __restrict__ k_pl,
    const float* __restrict__ v_pl,
    const int4* __restrict__ meta,  const int* __restrict__ row_start,
    float* __restrict__ num, float* __restrict__ den)
{
    const int tid = threadIdx.x;           // 0..511
    const int w   = tid & 127;             // lane = wo
    const int sub = tid >> 7;              // 0..3
    const bool aw = w < NLON;
    const int woc = aw ? w : (NLON - 1);
    const int ho  = blockIdx.x;
    const int head = blockIdx.z;           // 0..3
    const int cb  = head * 16;

    int e0 = __builtin_amdgcn_readfirstlane(row_start[ho]);
    int e1 = __builtin_amdgcn_readfirstlane(row_start[ho + 1]);
    int eb = e0 + blockIdx.y * ECHB;
    if (eb >= e1) return;                  // block-uniform: safe w.r.t. barrier
    int eeB = eb + ECHB; if (eeB > e1) eeB = e1;
    int es = eb + sub * SUBE;
    int ee = es + SUBE; if (ee > eeB) ee = eeB;

    const int segc = ho * NLON + woc;
    const float* __restrict__ qb = q_pl + (size_t)cb * NSEG;
    const float* __restrict__ kb = k_pl + (size_t)cb * NSEG;
    const float* __restrict__ vb = v_pl + (size_t)cb * NSEG;

    float qreg[16];
#pragma unroll
    for (int c = 0; c < 16; ++c) qreg[c] = qb[c * NSEG + segc];

    float acc[16];
#pragma unroll
    for (int c = 0; c < 16; ++c) acc[c] = 0.f;
    float dh = 0.f;

#pragma unroll 2
    for (int e = es; e < ee; ++e) {
        int4 mt = meta[e];
        int dlw = mt.y + woc; if (dlw >= NLON) dlw -= NLON;
        const float* __restrict__ kp = kb + (mt.x + dlw);
        const float* __restrict__ vp = vb + (mt.x + dlw);

        float sa = 0.f, sb = 0.f;
#pragma unroll
        for (int c = 0; c < 8; ++c)  sa += qreg[c]     * kp[c * NSEG];
#pragma unroll
        for (int c = 0; c < 8; ++c)  sb += qreg[8 + c] * kp[(8 + c) * NSEG];

        float qwv = aw ? __int_as_float(mt.z) : 0.f;
        float a = __expf(sa + sb) * qwv;
        dh += a;

#pragma unroll
        for (int c = 0; c < 16; ++c) acc[c] = fmaf(a, vp[c * NSEG], acc[c]);
    }

    // cross-subchunk reduction: red[c][tid] layout -> stride-1 across lanes,
    // conflict-free for both write and read phases.
    __shared__ float red[17][512];
#pragma unroll
    for (int c = 0; c < 16; ++c) red[c][tid] = acc[c];
    red[16][tid] = dh;
    __syncthreads();

    if (tid < 128 && aw) {
        const int seg = ho * NLON + w;
        const bool solo = (blockIdx.y == 0) & (e0 + ECHB >= e1);
        float dsum = red[16][w] + red[16][w + 128] + red[16][w + 256] + red[16][w + 384];
        if (solo) {
#pragma unroll
            for (int c = 0; c < 16; ++c) {
                float sv = red[c][w] + red[c][w + 128] + red[c][w + 256] + red[c][w + 384];
                num[(cb + c) * NSEG + seg] = sv;
            }
            den[head * NSEG + seg] = dsum;
        } else {
#pragma unroll
            for (int c = 0; c < 16; ++c) {
                float sv = red[c][w] + red[c][w + 128] + red[c][w + 256] + red[c][w + 384];
                atomicAdd(&num[(cb + c) * NSEG + seg], sv);
            }
            atomicAdd(&den[head * NSEG + seg], dsum);
        }
    }
}

// ---------------------------------------------------------------------------
// K2c: att = num/den, Wo projection + residual -> x1 planar.
// grid (115, 16): 4 output channels per group (R3: doubled wave count).
// ---------------------------------------------------------------------------
__global__ __launch_bounds__(64) void k2c_wo(
    const float* __restrict__ num, const float* __restrict__ den,
    const float* __restrict__ wo,  const float* __restrict__ x,
    float* __restrict__ x1)
{
    const int lane = threadIdx.x;
    const int n    = blockIdx.x * 64 + lane;
    if (n >= NSEG) return;

    float rdh[4];
#pragma unroll
    for (int h = 0; h < 4; ++h) rdh[h] = 1.0f / den[h * NSEG + n];

    float att[64];
#pragma unroll
    for (int c = 0; c < 64; ++c) att[c] = num[c * NSEG + n] * rdh[c >> 4];

    const int o0 = blockIdx.y * 4;
#pragma unroll
    for (int j = 0; j < 4; ++j) {
        int o = o0 + j;
        float acc = 0.f;
#pragma unroll
        for (int c = 0; c < 64; ++c) acc += wo[o * 64 + c] * att[c];
        x1[o * NSEG + n] = acc + x[o * NSEG + n];
    }
}

// ---------------------------------------------------------------------------
// K3a: LayerNorm1 + W1 + exact gelu -> m_act planar [128][NSEG].
// grid (115, 32): 4 hidden units per group (R3: 3680 waves).
// ---------------------------------------------------------------------------
__global__ __launch_bounds__(64) void k3a_mlp1(
    const float* __restrict__ x1, const float* __restrict__ w1,
    const float* __restrict__ b1, const float* __restrict__ g,
    const float* __restrict__ bb, float* __restrict__ m_act)
{
    const int lane = threadIdx.x;
    const int n    = blockIdx.x * 64 + lane;
    if (n >= NSEG) return;

    float xv[64];
    float s = 0.f, s2 = 0.f;
#pragma unroll
    for (int c = 0; c < 64; ++c) { float t = x1[c * NSEG + n]; xv[c] = t; s += t; s2 += t * t; }
    float mean = s * 0.015625f;
    float var  = s2 * 0.015625f - mean * mean;
    float rstd = rsqrtf(var + 1e-6f);
#pragma unroll
    for (int c = 0; c < 64; ++c) xv[c] = (xv[c] - mean) * rstd * g[c] + bb[c];

    const int h0 = blockIdx.y * 4;
#pragma unroll
    for (int j = 0; j < 4; ++j) {
        int h = h0 + j;
        float mh = b1[h];
#pragma unroll
        for (int c = 0; c < 64; ++c) mh += w1[h * 64 + c] * xv[c];
        m_act[h * NSEG + n] = 0.5f * mh * (1.0f + erff(mh * 0.70710678118654752f));
    }
}

// ---------------------------------------------------------------------------
// K3b: out = W2 * m_act + b2 + x1. grid (115, 16): 4 output channels/group.
// ---------------------------------------------------------------------------
__global__ __launch_bounds__(64) void k3b_mlp2(
    const float* __restrict__ m_act, const float* __restrict__ w2,
    const float* __restrict__ b2,    const float* __restrict__ x1,
    float* __restrict__ out)
{
    const int lane = threadIdx.x;
    const int n    = blockIdx.x * 64 + lane;
    if (n >= NSEG) return;
    const int c0   = blockIdx.y * 4;

    float acc[4];
#pragma unroll
    for (int j = 0; j < 4; ++j) acc[j] = 0.f;

#pragma unroll 8
    for (int h = 0; h < HIDN; ++h) {
        float mh = m_act[h * NSEG + n];
#pragma unroll
        for (int j = 0; j < 4; ++j) acc[j] += w2[(c0 + j) * HIDN + h] * mh;
    }
#pragma unroll
    for (int j = 0; j < 4; ++j) {
        int c = c0 + j;
        out[c * NSEG + n] = acc[j] + b2[c] + x1[c * NSEG + n];
    }
}

// ---------------------------------------------------------------------------
extern "C" void kernel_launch(void* const* d_in, const int* in_sizes, int n_in,
                              void* d_out, int out_size, void* d_ws, size_t ws_size,
                              hipStream_t stream)
{
    const float* x    = (const float*)d_in[0];
    const float* wq   = (const float*)d_in[1];
    const float* wk   = (const float*)d_in[2];
    const float* wv   = (const float*)d_in[3];
    const float* wo   = (const float*)d_in[4];
    const float* w1   = (const float*)d_in[5];
    const float* b1   = (const float*)d_in[6];
    const float* w2   = (const float*)d_in[7];
    const float* b2   = (const float*)d_in[8];
    const float* ln0g = (const float*)d_in[9];
    const float* ln0b = (const float*)d_in[10];
    const float* ln1g = (const float*)d_in[11];
    const float* ln1b = (const float*)d_in[12];
    const float* qw   = (const float*)d_in[13];
    const int* out_idx = (const int*)d_in[14];
    const int* in_idx  = (const int*)d_in[15];
    float* out = (float*)d_out;

    const int NNZ = in_sizes[15];
    const int E   = NNZ / NLON;
    const size_t N64 = (size_t)NSEG * 64;

    float* ws    = (float*)d_ws;
    float* q_pl  = ws;                     // [64][NSEG]
    float* k_pl  = ws + N64;
    float* v_pl  = ws + 2 * N64;
    float* num   = ws + 3 * N64;           // [64][NSEG]  (zeroed by k1)
    float* den   = ws + 4 * N64;           // [4][NSEG]   (zeroed, contiguous w/ num)
    float* x1    = ws + 4 * N64 + 4 * NSEG;
    float* m_act = ws + 5 * N64 + 4 * NSEG;           // [128][NSEG]
    int*   row_start = (int*)(ws + 7 * N64 + 4 * NSEG);            // [62]
    int4*  meta  = (int4*)(ws + 7 * N64 + 4 * NSEG + 64);          // [E]

    hipLaunchKernelGGL(k1_ln_qkv, dim3(115, 51), dim3(64), 0, stream,
                       x, wq, wk, wv, ln0g, ln0b, out_idx, in_idx, qw, E,
                       q_pl, k_pl, v_pl, row_start, meta, (float4*)num);
    hipLaunchKernelGGL(k2_attn, dim3(61, NCHB, 4), dim3(512), 0, stream,
                       q_pl, k_pl, v_pl, meta, row_start, num, den);
    hipLaunchKernelGGL(k2c_wo, dim3(115, 16), dim3(64), 0, stream,
                       num, den, wo, x, x1);
    hipLaunchKernelGGL(k3a_mlp1, dim3(115, 32), dim3(64), 0, stream,
                       x1, w1, b1, ln1g, ln1b, m_act);
    hipLaunchKernelGGL(k3b_mlp2, dim3(115, 16), dim3(64), 0, stream,
                       m_act, w2, b2, x1, out);
}